// Round 10
// baseline (179.791 us; speedup 1.0000x reference)
//
#include <hip/hip_runtime.h>

// SA_Head: B=4, S=4096, E=256, H=64
//   out = softmax((emb@wq)(emb@wk)^T / 16) (emb@wv)
// R14: fuse split-reduction into attn (last-block-finalize, flash-decoding
// pattern). The 4 split parts of each (b,qblk) land on the SAME XCD (bids
// p,p+8,p+16,p+24 share bid%8), so po is L2-resident for the finalizer:
// write po/pml -> threadfence -> atomicAdd(cnt[bq]); old==3 block re-reads
// the 4 parts + pml, normalizes, writes out. cnt[128] zeroed by prep_w
// (stream-ordered, re-zeroed each graph replay). reduce_kernel deleted.
// prep/proj/attn-loop = R13 verbatim.
// (R13: proj LDS-staged coalesced 16B-store epilogue. R12: 128q attn
//  blocks, all-keys-per-wave, LDS-staged K/V chunk^=row&7, split-K x4.
//  Base: XCD swizzle, no-max softmax |s|<=4, S^T-form QK keeps P in
//  registers, V pre-transposed vbt[h][s].)

typedef short short4v __attribute__((ext_vector_type(4)));
typedef short short8v __attribute__((ext_vector_type(8)));
typedef unsigned short ushort8v __attribute__((ext_vector_type(8)));
typedef float floatx4 __attribute__((ext_vector_type(4)));
typedef unsigned short u16;
typedef unsigned int u32;

#define SEQ 4096
#define EMB 256
#define HD 64
#define PADA 264   // u16 stride for proj A tile

static __device__ __forceinline__ u16 f2bf(float x) {
    union { float f; unsigned u; } v; v.f = x;
    unsigned r = v.u + 0x7FFFu + ((v.u >> 16) & 1u);
    return (u16)(r >> 16);
}

static __device__ __forceinline__ u32 cvt_pk_bf16(float a, float b) {
    u32 r;
    asm("v_cvt_pk_bf16_f32 %0, %1, %2" : "=v"(r) : "v"(a), "v"(b));
    return r;
}

static __device__ __forceinline__ short4v pack_bf4(float a, float b, float c, float d) {
    union { u32 u[2]; short4v s; } x;
    x.u[0] = cvt_pk_bf16(a, b);
    x.u[1] = cvt_pk_bf16(c, d);
    return x.s;
}

// ---------------- W prep: fragment-major Wt (+ zero finalize counters) -----------
__global__ __launch_bounds__(256) void prep_w(
    const float* __restrict__ wk, const float* __restrict__ wq, const float* __restrict__ wv,
    u16* __restrict__ wt, u32* __restrict__ cnt) {
    const int nt = blockIdx.x;   // 0..11
    const int t = threadIdx.x;
    if (nt == 0 && t < 128) cnt[t] = 0;
#pragma unroll
    for (int ss = 0; ss < 2; ++ss) {
        int slot = t + ss * 256;          // 0..511
        int kc = slot >> 6, lane = slot & 63;
        int ln15 = lane & 15, lq = lane >> 4;
        int cg = nt * 16 + ln15;
        int mat = cg >> 6, col = cg & 63;
        const float* W = (mat == 0) ? wq : (mat == 1) ? wk : wv;
        const float s = (mat == 0) ? 0.0625f * 1.44269504088896f : 1.0f;
        u32 w4[4];
#pragma unroll
        for (int p = 0; p < 2; ++p) {
#pragma unroll
            for (int d = 0; d < 2; ++d) {
                int e0 = kc * 32 + lq * 8 + p * 4 + d * 2;
                u16 lo = f2bf(W[(e0 + 0) * HD + col] * s);
                u16 hi = f2bf(W[(e0 + 1) * HD + col] * s);
                w4[p * 2 + d] = (u32)lo | ((u32)hi << 16);
            }
        }
        u32* dst = (u32*)wt + ((size_t)(nt * 8 + kc) * 64 + lane) * 4;
        *(uint4*)dst = make_uint4(w4[0], w4[1], w4[2], w4[3]);
    }
}

// ---------------- projection GEMM: [16384,256]@[256,192] bf16 MFMA ----------------
// grid 512 x 256; 32 rows/block.  Epilogue: acc -> LDS ot[12][32][16] ->
// coalesced 16B stores (Q/K row-stream, V gathered per-h into vbt[h][s]).
__global__ __launch_bounds__(256) void proj_mfma(
    const float* __restrict__ emb, const u16* __restrict__ wt,
    u16* __restrict__ qb, u16* __restrict__ kb, u16* __restrict__ vbt) {
    __shared__ u16 a_s[32 * PADA];
    __shared__ __align__(16) u16 ot_s[12][32][16];
    const int t = threadIdx.x;
    const int lane = t & 63;
    const int wave = t >> 6;
    const int ln15 = lane & 15;
    const int lq = lane >> 4;
    const size_t row0 = (size_t)blockIdx.x * 32;

#pragma unroll
    for (int c = 0; c < 8; ++c) {
        int f = t + c * 256;
        int row = f >> 6, e4 = (f & 63) * 4;
        float4 v = *(const float4*)(emb + (row0 + row) * EMB + e4);
        u32 lo = cvt_pk_bf16(v.x, v.y);
        u32 hi = cvt_pk_bf16(v.z, v.w);
        *(uint2*)&a_s[row * PADA + e4] = make_uint2(lo, hi);
    }
    __syncthreads();

    floatx4 acc[2][3];
#pragma unroll
    for (int rg = 0; rg < 2; ++rg)
#pragma unroll
        for (int j = 0; j < 3; ++j) {
            floatx4 z = { 0.f, 0.f, 0.f, 0.f };
            acc[rg][j] = z;
        }

#pragma unroll
    for (int kc = 0; kc < 8; ++kc) {
        short8v a0 = *(const short8v*)&a_s[ln15 * PADA + kc * 32 + lq * 8];
        short8v a1 = *(const short8v*)&a_s[(16 + ln15) * PADA + kc * 32 + lq * 8];
#pragma unroll
        for (int j = 0; j < 3; ++j) {
            short8v b = *(const short8v*)(wt + (((size_t)(wave * 3 + j) * 8 + kc) * 64 + lane) * 8);
            acc[0][j] = __builtin_amdgcn_mfma_f32_16x16x32_bf16(a0, b, acc[0][j], 0, 0, 0);
            acc[1][j] = __builtin_amdgcn_mfma_f32_16x16x32_bf16(a1, b, acc[1][j], 0, 0, 0);
        }
    }

    // stage results to LDS: ot[tile][row][col16]
#pragma unroll
    for (int rg = 0; rg < 2; ++rg)
#pragma unroll
        for (int j = 0; j < 3; ++j)
#pragma unroll
            for (int r = 0; r < 4; ++r)
                ot_s[wave * 3 + j][rg * 16 + lq * 4 + r][ln15] = f2bf(acc[rg][j][r]);
    __syncthreads();

    // Q/K: [row][64] stream -- thread f: row=f>>3, chunk=f&7
    {
        const int row = t >> 3, chunk = t & 7;
        const int tile = chunk >> 1, off = (chunk & 1) * 8;
        ushort8v qv = *(const ushort8v*)&ot_s[tile][row][off];
        *(ushort8v*)&qb[(row0 + row) * HD + chunk * 8] = qv;
        ushort8v kv = *(const ushort8v*)&ot_s[4 + tile][row][off];
        *(ushort8v*)&kb[(row0 + row) * HD + chunk * 8] = kv;
    }
    // V: thread f: h=f>>2, sc=f&3; gather 8 s-values -> 16B store
    {
        const int h = t >> 2, sc = t & 3;
        const int tile = 8 + (h >> 4), tcol = h & 15;
        union { u16 u[8]; ushort8v v; } g;
#pragma unroll
        for (int i = 0; i < 8; ++i)
            g.u[i] = ot_s[tile][sc * 8 + i][tcol];
        size_t bidx = row0 >> 12;
        size_t sl = (row0 & 4095) + sc * 8;
        *(ushort8v*)&vbt[(bidx * 64 + h) * SEQ + sl] = g.v;
    }
}

// ---------------- flash attention + fused split reduction -------------------------
// part = b*128 + qblk*4 + split; 4 waves; wave w owns q [q0+32w, +32) and
// ALL 64 keys of each staged tile.  After po/pml write: threadfence +
// atomicAdd(cnt[bq]); the 4th block re-reads the 4 parts (same-XCD L2),
// normalizes, writes out.

__global__ __launch_bounds__(256) void attn_kernel(
    const u16* __restrict__ qb, const u16* __restrict__ kb, const u16* __restrict__ vbt,
    float* __restrict__ po, float* __restrict__ pml,
    u32* __restrict__ cnt, float* __restrict__ out) {
    __shared__ __align__(16) u16 smem[4][64 * 64];   // [buf*2+{K,V}][64 rows x 128B]
    __shared__ float ls[128];
    __shared__ u32 amLast;

    const int t = threadIdx.x;
    const int lane = t & 63;
    const int wave = t >> 6;
    const int ln15 = lane & 15;
    const int lq = lane >> 4;

    // XCD-aware swizzle (512 blocks, 512%8==0 -> bijective)
    const int part = ((blockIdx.x & 7) << 6) | (blockIdx.x >> 3);
    const int b = part >> 7;
    const int qblk = (part >> 2) & 31;
    const int split = part & 3;
    const int q0 = qblk * 128;
    const int bq = part >> 2;            // 0..127

    const u16* __restrict__ qpb = qb + ((size_t)b * SEQ + q0) * HD;
    const u16* __restrict__ kpb = kb + (size_t)b * SEQ * HD;
    const u16* __restrict__ vpb = vbt + (size_t)b * HD * SEQ;

    // Q B-frags (loop-invariant): wave's q rows = q0 + wave*32 + nt*16 + ln15
    short8v qf[2][2];
#pragma unroll
    for (int nt = 0; nt < 2; ++nt)
#pragma unroll
        for (int h = 0; h < 2; ++h)
            qf[nt][h] = *(const short8v*)(qpb + (size_t)(wave * 32 + nt * 16 + ln15) * HD + h * 32 + lq * 8);

    floatx4 oacc[4][2];
#pragma unroll
    for (int ht = 0; ht < 4; ++ht)
#pragma unroll
        for (int nt = 0; nt < 2; ++nt) {
            floatx4 z = { 0.f, 0.f, 0.f, 0.f };
            oacc[ht][nt] = z;
        }
    float lacc[2] = { 0.f, 0.f };

    // staging geometry: flat f = t (+256): row = f>>3, chunk = f&7 (16B units).
    const int r0 = t >> 3, c0 = t & 7, r1 = r0 + 32;
    const int sw0 = r0 * 64 + ((c0 ^ (r0 & 7)) * 8);
    const int sw1 = r1 * 64 + ((c0 ^ (r1 & 7)) * 8);

    // frag read offsets (u16 units); kt adds kt*1024 (rows) / chunk kt*2 (V)
    const int xk = ln15 & 7;
    const int ksw_lo = ln15 * 64 + ((lq ^ xk) * 8);
    const int ksw_hi = ln15 * 64 + (((4 + lq) ^ xk) * 8);
    const int vch0 = lq >> 1, vsub = (lq & 1) * 4;

    uint4 ka, kb4, va, vb4;
    {   // prologue: stage tile 0 into buf 0
        const int kwb = (split * 16) * 64;
        ka  = *(const uint4*)(kpb + (size_t)(kwb + r0) * HD + c0 * 8);
        kb4 = *(const uint4*)(kpb + (size_t)(kwb + r1) * HD + c0 * 8);
        va  = *(const uint4*)(vpb + (size_t)r0 * SEQ + kwb + c0 * 8);
        vb4 = *(const uint4*)(vpb + (size_t)r1 * SEQ + kwb + c0 * 8);
        *(uint4*)(&smem[0][0] + sw0) = ka;
        *(uint4*)(&smem[0][0] + sw1) = kb4;
        *(uint4*)(&smem[1][0] + sw0) = va;
        *(uint4*)(&smem[1][0] + sw1) = vb4;
    }
    __syncthreads();

#pragma unroll 1
    for (int tt = 0; tt < 16; ++tt) {
        const int buf = tt & 1;
        // issue next tile's global loads (latency hidden under compute)
        if (tt < 15) {
            const int kwb = (split * 16 + tt + 1) * 64;
            ka  = *(const uint4*)(kpb + (size_t)(kwb + r0) * HD + c0 * 8);
            kb4 = *(const uint4*)(kpb + (size_t)(kwb + r1) * HD + c0 * 8);
            va  = *(const uint4*)(vpb + (size_t)r0 * SEQ + kwb + c0 * 8);
            vb4 = *(const uint4*)(vpb + (size_t)r1 * SEQ + kwb + c0 * 8);
        }

        const u16* ktp = &smem[buf * 2 + 0][0];
        const u16* vtp = &smem[buf * 2 + 1][0];

        // 4 x 16-key subtiles; wave covers all of them for its 32 q
#pragma unroll
        for (int kt = 0; kt < 4; ++kt) {
            short8v k0 = *(const short8v*)(ktp + kt * 1024 + ksw_lo);
            short8v k1 = *(const short8v*)(ktp + kt * 1024 + ksw_hi);

            floatx4 s[2];
            __builtin_amdgcn_s_setprio(1);
#pragma unroll
            for (int nt = 0; nt < 2; ++nt) {
                floatx4 z = { 0.f, 0.f, 0.f, 0.f };
                s[nt] = __builtin_amdgcn_mfma_f32_16x16x32_bf16(k0, qf[nt][0], z, 0, 0, 0);
                s[nt] = __builtin_amdgcn_mfma_f32_16x16x32_bf16(k1, qf[nt][1], s[nt], 0, 0, 0);
            }
            __builtin_amdgcn_s_setprio(0);

            short4v pf[2];
#pragma unroll
            for (int nt = 0; nt < 2; ++nt) {
                float p0 = __builtin_amdgcn_exp2f(s[nt][0]);
                float p1 = __builtin_amdgcn_exp2f(s[nt][1]);
                float p2 = __builtin_amdgcn_exp2f(s[nt][2]);
                float p3 = __builtin_amdgcn_exp2f(s[nt][3]);
                lacc[nt] += (p0 + p1) + (p2 + p3);
                pf[nt] = pack_bf4(p0, p1, p2, p3);
            }

            __builtin_amdgcn_s_setprio(1);
#pragma unroll
            for (int ht = 0; ht < 4; ++ht) {
                short4v vf = *(const short4v*)(vtp + ht * 1024 + ln15 * 64
                               + (((kt * 2 + vch0) ^ xk) * 8) + vsub);
#pragma unroll
                for (int nt = 0; nt < 2; ++nt)
                    oacc[ht][nt] = __builtin_amdgcn_mfma_f32_16x16x16bf16_1k(
                        vf, pf[nt], oacc[ht][nt], 0, 0, 0);
            }
            __builtin_amdgcn_s_setprio(0);
        }

        // write next tile to the other LDS buffer
        if (tt < 15) {
            u16* ktn = &smem[(buf ^ 1) * 2 + 0][0];
            u16* vtn = &smem[(buf ^ 1) * 2 + 1][0];
            *(uint4*)(ktn + sw0) = ka;
            *(uint4*)(ktn + sw1) = kb4;
            *(uint4*)(vtn + sw0) = va;
            *(uint4*)(vtn + sw1) = vb4;
        }
        __syncthreads();
    }

    // ---- epilogue: in-wave l reduce, po/pml write ----
#pragma unroll
    for (int nt = 0; nt < 2; ++nt) {
        lacc[nt] += __shfl_xor(lacc[nt], 16);
        lacc[nt] += __shfl_xor(lacc[nt], 32);
    }
    if (lq == 0) {
#pragma unroll
        for (int nt = 0; nt < 2; ++nt)
            pml[(size_t)part * 128 + wave * 32 + nt * 16 + ln15] = lacc[nt];
    }

    // po[part][q][h], q = wave*32+nt*16+ln15, h = ht*16+lq*4+r (float4 stores)
    float* __restrict__ pob = po + (size_t)part * 8192;
#pragma unroll
    for (int ht = 0; ht < 4; ++ht)
#pragma unroll
        for (int nt = 0; nt < 2; ++nt)
            *(floatx4*)&pob[(wave * 32 + nt * 16 + ln15) * 64 + ht * 16 + lq * 4] = oacc[ht][nt];

    // ---- fused split reduction: last block for this bq finalizes ----
    __threadfence();          // release: po/pml visible before the count
    __syncthreads();          // all threads' stores issued + fenced
    if (t == 0) {
        u32 old = atomicAdd(&cnt[bq], 1u);
        amLast = (old == 3u);
    }
    __syncthreads();
    if (!amLast) return;
    __threadfence();          // acquire: order po reads after count observation

    const int part0 = bq * 4;
    if (t < 128)
        ls[t] = pml[(size_t)(part0 + 0) * 128 + t] + pml[(size_t)(part0 + 1) * 128 + t]
              + pml[(size_t)(part0 + 2) * 128 + t] + pml[(size_t)(part0 + 3) * 128 + t];
    __syncthreads();

    const float* __restrict__ p0 = po + (size_t)(part0 + 0) * 8192;
    const float* __restrict__ p1 = po + (size_t)(part0 + 1) * 8192;
    const float* __restrict__ p2 = po + (size_t)(part0 + 2) * 8192;
    const float* __restrict__ p3 = po + (size_t)(part0 + 3) * 8192;
    float* __restrict__ ob = out + ((size_t)b * SEQ + (size_t)qblk * 128) * HD;

#pragma unroll
    for (int i = 0; i < 8; ++i) {
        int f4 = t + i * 256;            // 0..2047
        int f = f4 * 4;
        int q = f4 >> 4;
        float4 a = *(const float4*)&p0[f];
        float4 c = *(const float4*)&p1[f];
        float4 d = *(const float4*)&p2[f];
        float4 e = *(const float4*)&p3[f];
        float inv = 1.0f / ls[q];
        float4 r;
        r.x = (a.x + c.x + d.x + e.x) * inv;
        r.y = (a.y + c.y + d.y + e.y) * inv;
        r.z = (a.z + c.z + d.z + e.z) * inv;
        r.w = (a.w + c.w + d.w + e.w) * inv;
        *(float4*)&ob[f] = r;
    }
}

extern "C" void kernel_launch(void* const* d_in, const int* in_sizes, int n_in,
                              void* d_out, int out_size, void* d_ws, size_t ws_size,
                              hipStream_t stream) {
    const float* emb = (const float*)d_in[0];
    const float* wk  = (const float*)d_in[1];
    const float* wq  = (const float*)d_in[2];
    const float* wv  = (const float*)d_in[3];

    // ws: qb 2M @0, kb 2M @2M, vbt 2M @4M, wt 96K @6M, po 16M @6.25M,
    //     pml 256K @22.25M, cnt 512B @23M
    u16* qb  = (u16*)d_ws;
    u16* kb  = (u16*)((char*)d_ws + (size_t)2 * 1024 * 1024);
    u16* vbt = (u16*)((char*)d_ws + (size_t)4 * 1024 * 1024);
    u16* wt  = (u16*)((char*)d_ws + (size_t)6 * 1024 * 1024);
    float* po  = (float*)((char*)d_ws + (size_t)6 * 1024 * 1024 + 256 * 1024);
    float* pml = (float*)((char*)d_ws + (size_t)22 * 1024 * 1024 + 256 * 1024);
    u32* cnt = (u32*)((char*)d_ws + (size_t)23 * 1024 * 1024);
    float* out = (float*)d_out;

    prep_w<<<12, 256, 0, stream>>>(wk, wq, wv, wt, cnt);
    proj_mfma<<<512, 256, 0, stream>>>(emb, wt, qb, kb, vbt);
    attn_kernel<<<512, 256, 0, stream>>>(qb, kb, vbt, po, pml, cnt, out);
}

// Round 11
// 114.776 us; speedup vs baseline: 1.5665x; 1.5665x over previous
//
#include <hip/hip_runtime.h>

// SA_Head: B=4, S=4096, E=256, H=64
//   out = softmax((emb@wq)(emb@wk)^T / 16) (emb@wv)
// R15: revert R14's fused reduction (device-scope threadfence = per-block L2
// writeback/invalidate -> attn 108us, FETCH x2.6; separate reduce is cheaper).
// Back to R13, ONE change: split-K 4->8 (grid 1024, 8 tt/block). Staging
// traffic is split-invariant; po spill 16->32MB (+~2.5us) buys occupancy
// 2->4 blocks/CU so co-resident blocks overlap each other's per-tt
// drain/ds_write/barrier serialization (all pipes were <30% busy).
// (R13: proj LDS-staged coalesced 16B-store epilogue. R12: 128q attn
//  blocks, all-keys-per-wave, LDS-staged K/V chunk^=row&7, T14 split
//  staging. Base: XCD swizzle, no-max softmax |s|<=4, S^T-form QK keeps
//  P in registers, V pre-transposed vbt[h][s].)

typedef short short4v __attribute__((ext_vector_type(4)));
typedef short short8v __attribute__((ext_vector_type(8)));
typedef unsigned short ushort8v __attribute__((ext_vector_type(8)));
typedef float floatx4 __attribute__((ext_vector_type(4)));
typedef unsigned short u16;
typedef unsigned int u32;

#define SEQ 4096
#define EMB 256
#define HD 64
#define PADA 264   // u16 stride for proj A tile

static __device__ __forceinline__ u16 f2bf(float x) {
    union { float f; unsigned u; } v; v.f = x;
    unsigned r = v.u + 0x7FFFu + ((v.u >> 16) & 1u);
    return (u16)(r >> 16);
}

static __device__ __forceinline__ u32 cvt_pk_bf16(float a, float b) {
    u32 r;
    asm("v_cvt_pk_bf16_f32 %0, %1, %2" : "=v"(r) : "v"(a), "v"(b));
    return r;
}

static __device__ __forceinline__ short4v pack_bf4(float a, float b, float c, float d) {
    union { u32 u[2]; short4v s; } x;
    x.u[0] = cvt_pk_bf16(a, b);
    x.u[1] = cvt_pk_bf16(c, d);
    return x.s;
}

// ---------------- W prep: fragment-major Wt --------------------------------------
__global__ __launch_bounds__(256) void prep_w(
    const float* __restrict__ wk, const float* __restrict__ wq, const float* __restrict__ wv,
    u16* __restrict__ wt) {
    const int nt = blockIdx.x;   // 0..11
    const int t = threadIdx.x;
#pragma unroll
    for (int ss = 0; ss < 2; ++ss) {
        int slot = t + ss * 256;          // 0..511
        int kc = slot >> 6, lane = slot & 63;
        int ln15 = lane & 15, lq = lane >> 4;
        int cg = nt * 16 + ln15;
        int mat = cg >> 6, col = cg & 63;
        const float* W = (mat == 0) ? wq : (mat == 1) ? wk : wv;
        const float s = (mat == 0) ? 0.0625f * 1.44269504088896f : 1.0f;
        u32 w4[4];
#pragma unroll
        for (int p = 0; p < 2; ++p) {
#pragma unroll
            for (int d = 0; d < 2; ++d) {
                int e0 = kc * 32 + lq * 8 + p * 4 + d * 2;
                u16 lo = f2bf(W[(e0 + 0) * HD + col] * s);
                u16 hi = f2bf(W[(e0 + 1) * HD + col] * s);
                w4[p * 2 + d] = (u32)lo | ((u32)hi << 16);
            }
        }
        u32* dst = (u32*)wt + ((size_t)(nt * 8 + kc) * 64 + lane) * 4;
        *(uint4*)dst = make_uint4(w4[0], w4[1], w4[2], w4[3]);
    }
}

// ---------------- projection GEMM: [16384,256]@[256,192] bf16 MFMA ----------------
// grid 512 x 256; 32 rows/block.  Epilogue: acc -> LDS ot[12][32][16] ->
// coalesced 16B stores (Q/K row-stream, V gathered per-h into vbt[h][s]).
__global__ __launch_bounds__(256) void proj_mfma(
    const float* __restrict__ emb, const u16* __restrict__ wt,
    u16* __restrict__ qb, u16* __restrict__ kb, u16* __restrict__ vbt) {
    __shared__ u16 a_s[32 * PADA];
    __shared__ __align__(16) u16 ot_s[12][32][16];
    const int t = threadIdx.x;
    const int lane = t & 63;
    const int wave = t >> 6;
    const int ln15 = lane & 15;
    const int lq = lane >> 4;
    const size_t row0 = (size_t)blockIdx.x * 32;

#pragma unroll
    for (int c = 0; c < 8; ++c) {
        int f = t + c * 256;
        int row = f >> 6, e4 = (f & 63) * 4;
        float4 v = *(const float4*)(emb + (row0 + row) * EMB + e4);
        u32 lo = cvt_pk_bf16(v.x, v.y);
        u32 hi = cvt_pk_bf16(v.z, v.w);
        *(uint2*)&a_s[row * PADA + e4] = make_uint2(lo, hi);
    }
    __syncthreads();

    floatx4 acc[2][3];
#pragma unroll
    for (int rg = 0; rg < 2; ++rg)
#pragma unroll
        for (int j = 0; j < 3; ++j) {
            floatx4 z = { 0.f, 0.f, 0.f, 0.f };
            acc[rg][j] = z;
        }

#pragma unroll
    for (int kc = 0; kc < 8; ++kc) {
        short8v a0 = *(const short8v*)&a_s[ln15 * PADA + kc * 32 + lq * 8];
        short8v a1 = *(const short8v*)&a_s[(16 + ln15) * PADA + kc * 32 + lq * 8];
#pragma unroll
        for (int j = 0; j < 3; ++j) {
            short8v b = *(const short8v*)(wt + (((size_t)(wave * 3 + j) * 8 + kc) * 64 + lane) * 8);
            acc[0][j] = __builtin_amdgcn_mfma_f32_16x16x32_bf16(a0, b, acc[0][j], 0, 0, 0);
            acc[1][j] = __builtin_amdgcn_mfma_f32_16x16x32_bf16(a1, b, acc[1][j], 0, 0, 0);
        }
    }

    // stage results to LDS: ot[tile][row][col16]
#pragma unroll
    for (int rg = 0; rg < 2; ++rg)
#pragma unroll
        for (int j = 0; j < 3; ++j)
#pragma unroll
            for (int r = 0; r < 4; ++r)
                ot_s[wave * 3 + j][rg * 16 + lq * 4 + r][ln15] = f2bf(acc[rg][j][r]);
    __syncthreads();

    // Q/K: [row][64] stream -- thread f: row=f>>3, chunk=f&7
    {
        const int row = t >> 3, chunk = t & 7;
        const int tile = chunk >> 1, off = (chunk & 1) * 8;
        ushort8v qv = *(const ushort8v*)&ot_s[tile][row][off];
        *(ushort8v*)&qb[(row0 + row) * HD + chunk * 8] = qv;
        ushort8v kv = *(const ushort8v*)&ot_s[4 + tile][row][off];
        *(ushort8v*)&kb[(row0 + row) * HD + chunk * 8] = kv;
    }
    // V: thread f: h=f>>2, sc=f&3; gather 8 s-values -> 16B store
    {
        const int h = t >> 2, sc = t & 3;
        const int tile = 8 + (h >> 4), tcol = h & 15;
        union { u16 u[8]; ushort8v v; } g;
#pragma unroll
        for (int i = 0; i < 8; ++i)
            g.u[i] = ot_s[tile][sc * 8 + i][tcol];
        size_t bidx = row0 >> 12;
        size_t sl = (row0 & 4095) + sc * 8;
        *(ushort8v*)&vbt[(bidx * 64 + h) * SEQ + sl] = g.v;
    }
}

// ---------------- flash attention: LDS-staged tiles, 128q blocks, split-K x8 ------
// part = b*256 + qblk*8 + split; 4 waves; wave w owns q [q0+32w, +32) and
// ALL 64 keys of each staged tile.  Per tt: K[64k][64d], V^T[64h][64k] in
// LDS (coalesced, chunk^=row&7 swizzle); per 16-key subtile kt:
// S^T = K.Q^T (16x16x32), P = exp2 in-reg, O^T += V^T.P (16x16x16).
// No cross-wave O reduce: wave writes its finished 32q x 64h to po.

__global__ __launch_bounds__(256) void attn_kernel(
    const u16* __restrict__ qb, const u16* __restrict__ kb, const u16* __restrict__ vbt,
    float* __restrict__ po, float* __restrict__ pml) {
    __shared__ __align__(16) u16 smem[4][64 * 64];   // [buf*2+{K,V}][64 rows x 128B]

    const int t = threadIdx.x;
    const int lane = t & 63;
    const int wave = t >> 6;
    const int ln15 = lane & 15;
    const int lq = lane >> 4;

    // XCD-aware swizzle (1024 blocks, 1024%8==0 -> bijective)
    const int part = ((blockIdx.x & 7) << 7) | (blockIdx.x >> 3);
    const int b = part >> 8;
    const int qblk = (part >> 3) & 31;
    const int split = part & 7;
    const int q0 = qblk * 128;

    const u16* __restrict__ qpb = qb + ((size_t)b * SEQ + q0) * HD;
    const u16* __restrict__ kpb = kb + (size_t)b * SEQ * HD;
    const u16* __restrict__ vpb = vbt + (size_t)b * HD * SEQ;

    // Q B-frags (loop-invariant): wave's q rows = q0 + wave*32 + nt*16 + ln15
    short8v qf[2][2];
#pragma unroll
    for (int nt = 0; nt < 2; ++nt)
#pragma unroll
        for (int h = 0; h < 2; ++h)
            qf[nt][h] = *(const short8v*)(qpb + (size_t)(wave * 32 + nt * 16 + ln15) * HD + h * 32 + lq * 8);

    floatx4 oacc[4][2];
#pragma unroll
    for (int ht = 0; ht < 4; ++ht)
#pragma unroll
        for (int nt = 0; nt < 2; ++nt) {
            floatx4 z = { 0.f, 0.f, 0.f, 0.f };
            oacc[ht][nt] = z;
        }
    float lacc[2] = { 0.f, 0.f };

    // staging geometry: flat f = t (+256): row = f>>3, chunk = f&7 (16B units).
    const int r0 = t >> 3, c0 = t & 7, r1 = r0 + 32;
    const int sw0 = r0 * 64 + ((c0 ^ (r0 & 7)) * 8);
    const int sw1 = r1 * 64 + ((c0 ^ (r1 & 7)) * 8);

    // frag read offsets (u16 units); kt adds kt*1024 (rows) / chunk kt*2 (V)
    const int xk = ln15 & 7;
    const int ksw_lo = ln15 * 64 + ((lq ^ xk) * 8);
    const int ksw_hi = ln15 * 64 + (((4 + lq) ^ xk) * 8);
    const int vch0 = lq >> 1, vsub = (lq & 1) * 4;

    uint4 ka, kb4, va, vb4;
    {   // prologue: stage tile 0 into buf 0
        const int kwb = (split * 8) * 64;
        ka  = *(const uint4*)(kpb + (size_t)(kwb + r0) * HD + c0 * 8);
        kb4 = *(const uint4*)(kpb + (size_t)(kwb + r1) * HD + c0 * 8);
        va  = *(const uint4*)(vpb + (size_t)r0 * SEQ + kwb + c0 * 8);
        vb4 = *(const uint4*)(vpb + (size_t)r1 * SEQ + kwb + c0 * 8);
        *(uint4*)(&smem[0][0] + sw0) = ka;
        *(uint4*)(&smem[0][0] + sw1) = kb4;
        *(uint4*)(&smem[1][0] + sw0) = va;
        *(uint4*)(&smem[1][0] + sw1) = vb4;
    }
    __syncthreads();

#pragma unroll 1
    for (int tt = 0; tt < 8; ++tt) {
        const int buf = tt & 1;
        // issue next tile's global loads (latency hidden under compute)
        if (tt < 7) {
            const int kwb = (split * 8 + tt + 1) * 64;
            ka  = *(const uint4*)(kpb + (size_t)(kwb + r0) * HD + c0 * 8);
            kb4 = *(const uint4*)(kpb + (size_t)(kwb + r1) * HD + c0 * 8);
            va  = *(const uint4*)(vpb + (size_t)r0 * SEQ + kwb + c0 * 8);
            vb4 = *(const uint4*)(vpb + (size_t)r1 * SEQ + kwb + c0 * 8);
        }

        const u16* ktp = &smem[buf * 2 + 0][0];
        const u16* vtp = &smem[buf * 2 + 1][0];

        // 4 x 16-key subtiles; wave covers all of them for its 32 q
#pragma unroll
        for (int kt = 0; kt < 4; ++kt) {
            short8v k0 = *(const short8v*)(ktp + kt * 1024 + ksw_lo);
            short8v k1 = *(const short8v*)(ktp + kt * 1024 + ksw_hi);

            floatx4 s[2];
            __builtin_amdgcn_s_setprio(1);
#pragma unroll
            for (int nt = 0; nt < 2; ++nt) {
                floatx4 z = { 0.f, 0.f, 0.f, 0.f };
                s[nt] = __builtin_amdgcn_mfma_f32_16x16x32_bf16(k0, qf[nt][0], z, 0, 0, 0);
                s[nt] = __builtin_amdgcn_mfma_f32_16x16x32_bf16(k1, qf[nt][1], s[nt], 0, 0, 0);
            }
            __builtin_amdgcn_s_setprio(0);

            short4v pf[2];
#pragma unroll
            for (int nt = 0; nt < 2; ++nt) {
                float p0 = __builtin_amdgcn_exp2f(s[nt][0]);
                float p1 = __builtin_amdgcn_exp2f(s[nt][1]);
                float p2 = __builtin_amdgcn_exp2f(s[nt][2]);
                float p3 = __builtin_amdgcn_exp2f(s[nt][3]);
                lacc[nt] += (p0 + p1) + (p2 + p3);
                pf[nt] = pack_bf4(p0, p1, p2, p3);
            }

            __builtin_amdgcn_s_setprio(1);
#pragma unroll
            for (int ht = 0; ht < 4; ++ht) {
                short4v vf = *(const short4v*)(vtp + ht * 1024 + ln15 * 64
                               + (((kt * 2 + vch0) ^ xk) * 8) + vsub);
#pragma unroll
                for (int nt = 0; nt < 2; ++nt)
                    oacc[ht][nt] = __builtin_amdgcn_mfma_f32_16x16x16bf16_1k(
                        vf, pf[nt], oacc[ht][nt], 0, 0, 0);
            }
            __builtin_amdgcn_s_setprio(0);
        }

        // write next tile to the other LDS buffer
        if (tt < 7) {
            u16* ktn = &smem[(buf ^ 1) * 2 + 0][0];
            u16* vtn = &smem[(buf ^ 1) * 2 + 1][0];
            *(uint4*)(ktn + sw0) = ka;
            *(uint4*)(ktn + sw1) = kb4;
            *(uint4*)(vtn + sw0) = va;
            *(uint4*)(vtn + sw1) = vb4;
        }
        __syncthreads();
    }

    // ---- epilogue: in-wave l reduce, direct po write (no cross-wave O) ----
#pragma unroll
    for (int nt = 0; nt < 2; ++nt) {
        lacc[nt] += __shfl_xor(lacc[nt], 16);
        lacc[nt] += __shfl_xor(lacc[nt], 32);
    }
    if (lq == 0) {
#pragma unroll
        for (int nt = 0; nt < 2; ++nt)
            pml[(size_t)part * 128 + wave * 32 + nt * 16 + ln15] = lacc[nt];
    }

    // po[part][q][h], q = wave*32+nt*16+ln15, h = ht*16+lq*4+r (float4 stores)
    float* __restrict__ pob = po + (size_t)part * 8192;
#pragma unroll
    for (int ht = 0; ht < 4; ++ht)
#pragma unroll
        for (int nt = 0; nt < 2; ++nt)
            *(floatx4*)&pob[(wave * 32 + nt * 16 + ln15) * 64 + ht * 16 + lq * 4] = oacc[ht][nt];
}

// ---------------- split reduction: sum 8 splits, normalize (pure f4 stream) -------
__global__ __launch_bounds__(256) void reduce_kernel(
    const float* __restrict__ po, const float* __restrict__ pml,
    float* __restrict__ out) {
    __shared__ float ls[128];
    const int t = threadIdx.x;
    const int bq = blockIdx.x >> 1;      // 0..127: b = bq>>5, qblk = bq&31
    const int half = blockIdx.x & 1;
    const int part0 = bq * 8;

    if (t < 128) {
        float a = 0.f;
#pragma unroll
        for (int p = 0; p < 8; ++p)
            a += pml[(size_t)(part0 + p) * 128 + t];
        ls[t] = a;
    }
    __syncthreads();

    float* __restrict__ ob = out + ((size_t)(bq >> 5) * SEQ + (size_t)(bq & 31) * 128) * HD;

#pragma unroll
    for (int i = 0; i < 4; ++i) {
        int f4 = half * 1024 + t + i * 256;   // 0..2047
        int f = f4 * 4;
        int q = f4 >> 4;
        float4 r0 = *(const float4*)&po[(size_t)(part0 + 0) * 8192 + f];
#pragma unroll
        for (int p = 1; p < 8; ++p) {
            float4 x = *(const float4*)&po[(size_t)(part0 + p) * 8192 + f];
            r0.x += x.x; r0.y += x.y; r0.z += x.z; r0.w += x.w;
        }
        float inv = 1.0f / ls[q];
        r0.x *= inv; r0.y *= inv; r0.z *= inv; r0.w *= inv;
        *(float4*)&ob[f] = r0;
    }
}

extern "C" void kernel_launch(void* const* d_in, const int* in_sizes, int n_in,
                              void* d_out, int out_size, void* d_ws, size_t ws_size,
                              hipStream_t stream) {
    const float* emb = (const float*)d_in[0];
    const float* wk  = (const float*)d_in[1];
    const float* wq  = (const float*)d_in[2];
    const float* wv  = (const float*)d_in[3];

    // ws: qb 2M @0, kb 2M @2M, vbt 2M @4M, wt 96K @6M, po 32M @6.25M,
    //     pml 512K @38.5M
    u16* qb  = (u16*)d_ws;
    u16* kb  = (u16*)((char*)d_ws + (size_t)2 * 1024 * 1024);
    u16* vbt = (u16*)((char*)d_ws + (size_t)4 * 1024 * 1024);
    u16* wt  = (u16*)((char*)d_ws + (size_t)6 * 1024 * 1024);
    float* po  = (float*)((char*)d_ws + (size_t)6 * 1024 * 1024 + 256 * 1024);
    float* pml = (float*)((char*)d_ws + (size_t)38 * 1024 * 1024 + 512 * 1024);
    float* out = (float*)d_out;

    prep_w<<<12, 256, 0, stream>>>(wk, wq, wv, wt);
    proj_mfma<<<512, 256, 0, stream>>>(emb, wt, qb, kb, vbt);
    attn_kernel<<<1024, 256, 0, stream>>>(qb, kb, vbt, po, pml);
    reduce_kernel<<<256, 256, 0, stream>>>(po, pml, out);
}